// Round 10
// baseline (369.026 us; speedup 1.0000x reference)
//
#include <hip/hip_runtime.h>
#include <hip/hip_bf16.h>
#include <cstdint>

typedef __attribute__((ext_vector_type(4))) float f32x4;
typedef _Float16 f16x8 __attribute__((ext_vector_type(8)));
typedef _Float16 f16x4 __attribute__((ext_vector_type(4)));

#define BN_EPS 1e-5f

// ---------------- fp32 -> fp16 cast (only W needs it now) ----------------
__global__ __launch_bounds__(256)
void cast_f32_f16(const float* __restrict__ src, _Float16* __restrict__ dst, int n8) {
    int i = blockIdx.x * blockDim.x + threadIdx.x;
    if (i >= n8) return;
    const float4* s4 = (const float4*)src;
    float4 a = s4[2 * (size_t)i];
    float4 b = s4[2 * (size_t)i + 1];
    f16x8 h;
    h[0] = (_Float16)a.x; h[1] = (_Float16)a.y; h[2] = (_Float16)a.z; h[3] = (_Float16)a.w;
    h[4] = (_Float16)b.x; h[5] = (_Float16)b.y; h[6] = (_Float16)b.z; h[7] = (_Float16)b.w;
    *(f16x8*)(dst + 8 * (size_t)i) = h;
}

// async global->LDS, 16B per lane, wave-uniform LDS base (B path only)
__device__ __forceinline__ void async16(const char* g, char* l) {
    __builtin_amdgcn_global_load_lds(
        (const __attribute__((address_space(1))) unsigned int*)(uintptr_t)g,
        (__attribute__((address_space(3))) unsigned int*)(uintptr_t)l,
        16, 0, 0);
}

// ============== 8-phase GEMM with FUSED A-cast: 256x256, BK=64, k-split phases ==============
// A is fp32 in global: reg-staged (global_load_dwordx4 -> cvt f16 -> ds_write_b64 into the
// SAME swizzled f16 layout the reads use; write-swz == read-swz, rule #21). B = pre-cast W
// f16 via global_load_lds (linear dest + pre-permuted source, proven r3-r9, 0 conflicts).
// Per tile t (4 phases, reads/MFMA identical to r9):
//  P1: dsRead Bk0+A(mh0)k0 | issue A j0-3 (t+1, dwordx4) + 4x gload_lds B(t+1) | bar lgkm0 MFMA bar
//  P2: dsRead A(mh1)k0     | issue A j4-7 (t+1)                               | bar lgkm0 MFMA bar
//  P3: dsRead Bk1+A(mh0)k1 | vmcnt(8): FIFO {Aj03(4),B(4),Aj47(4)} retires Aj03; cvt+ds_write | bar lgkm0 MFMA bar
//  P4: dsRead A(mh1)k1     | bar lgkm0 MFMA; vmcnt(0) (loads 2-3 phases old); cvt+ds_write j4-7;
//      lgkm0 (write visibility) ; bar
// Buffer safety: writes target parity(t+1)==parity(t-1), whose reads drained >=2 barriers ago.

#define LDSA(h, par) (lds + (h) * 32768 + (par) * 16384)
#define LDSB(h, par) (lds + 65536 + (h) * 32768 + (par) * 16384)

__device__ __forceinline__ void dsReadB(f16x8 (&b)[4], const char* bh, int boff) {
    #pragma unroll
    for (int n = 0; n < 4; ++n) b[n] = *(const f16x8*)(bh + boff + n * 1024);
}
template<int MH>
__device__ __forceinline__ void dsReadA(f16x8 (&a)[4], const char* ah, int aoff) {
    #pragma unroll
    for (int m = 0; m < 4; ++m) a[m] = *(const f16x8*)(ah + aoff + MH * 4096 + m * 1024);
}
template<int MH>
__device__ __forceinline__ void mfma16(const f16x8 (&a)[4], const f16x8 (&b)[4], f32x4 (&acc)[8][4]) {
    __builtin_amdgcn_s_setprio(1);
    #pragma unroll
    for (int m = 0; m < 4; ++m)
        #pragma unroll
        for (int n = 0; n < 4; ++n)
            acc[MH * 4 + m][n] = __builtin_amdgcn_mfma_f32_16x16x32_f16(a[m], b[n], acc[MH * 4 + m][n], 0, 0, 0);
    __builtin_amdgcn_s_setprio(0);
}

__device__ __forceinline__ void cvtWrite(char* addr, const float4& v) {
    f16x4 h;
    h[0] = (_Float16)v.x; h[1] = (_Float16)v.y; h[2] = (_Float16)v.z; h[3] = (_Float16)v.w;
    *(f16x4*)addr = h;
}

template<bool STAGE>
__device__ __forceinline__ void ktile(
    int kt, char* lds,
    const float* aTh, const char* b0, const char* b1,
    int widB, int aoff, int boff, const int (&wA)[8],
    f32x4 (&acc)[8][4], int K)
{
    const int par = kt & 1, nxt = par ^ 1;
    const char* A0h = LDSA(0, par); const char* A1h = LDSA(1, par);
    const char* B0h = LDSB(0, par); const char* B1h = LDSB(1, par);
    f16x8 a[4], b[4];
    float4 rA[8];
    const size_t cfp = (size_t)(kt + 1) * 64;     // fp32 col offset of tile kt+1 in A
    const size_t cbB = (size_t)(kt + 1) * 128;    // byte col offset of tile kt+1 in W f16

    // ---- P1: ks0, mh0 ----
    dsReadB(b, B0h, boff);
    dsReadA<0>(a, A0h, aoff);
    if (STAGE) {
        #pragma unroll
        for (int j = 0; j < 4; ++j)
            rA[j] = *(const float4*)(aTh + (size_t)(32 * j) * K + cfp);
        async16(b0 + cbB,      LDSB(0, nxt) + widB);
        async16(b1 + cbB,      LDSB(0, nxt) + 8192 + widB);
        async16(b0 + cbB + 64, LDSB(1, nxt) + widB);
        async16(b1 + cbB + 64, LDSB(1, nxt) + 8192 + widB);
    }
    __builtin_amdgcn_s_barrier();
    asm volatile("s_waitcnt lgkmcnt(0)" ::: "memory");
    mfma16<0>(a, b, acc);
    __builtin_amdgcn_s_barrier();

    // ---- P2: ks0, mh1 ----
    dsReadA<1>(a, A0h, aoff);
    if (STAGE) {
        #pragma unroll
        for (int j = 4; j < 8; ++j)
            rA[j] = *(const float4*)(aTh + (size_t)(32 * j) * K + cfp);
    }
    __builtin_amdgcn_s_barrier();
    asm volatile("s_waitcnt lgkmcnt(0)" ::: "memory");
    mfma16<1>(a, b, acc);
    __builtin_amdgcn_s_barrier();

    // ---- P3: ks1, mh0 ----
    dsReadB(b, B1h, boff);
    dsReadA<0>(a, A1h, aoff);
    if (STAGE) {
        asm volatile("s_waitcnt vmcnt(8)" ::: "memory");   // retires A j0-3 (oldest 4 of 12)
        char* base = lds + nxt * 16384;
        #pragma unroll
        for (int j = 0; j < 4; ++j) cvtWrite(base + wA[j], rA[j]);
    }
    __builtin_amdgcn_s_barrier();
    asm volatile("s_waitcnt lgkmcnt(0)" ::: "memory");
    mfma16<0>(a, b, acc);
    __builtin_amdgcn_s_barrier();

    // ---- P4: ks1, mh1 ----
    dsReadA<1>(a, A1h, aoff);
    __builtin_amdgcn_s_barrier();
    asm volatile("s_waitcnt lgkmcnt(0)" ::: "memory");
    mfma16<1>(a, b, acc);
    if (STAGE) {
        asm volatile("s_waitcnt vmcnt(0)" ::: "memory");   // A j4-7 + B(t+1) (2-3 phases old)
        char* base = lds + nxt * 16384;
        #pragma unroll
        for (int j = 4; j < 8; ++j) cvtWrite(base + wA[j], rA[j]);
        asm volatile("s_waitcnt lgkmcnt(0)" ::: "memory"); // writes visible before barrier
    }
    __builtin_amdgcn_s_barrier();
}

__global__ __launch_bounds__(512, 2)
void gemm_gbn_kernel(const float* __restrict__ Af,
                     const _Float16* __restrict__ Bw,
                     const float* __restrict__ priors,
                     const float* __restrict__ gamma,
                     const float* __restrict__ beta,
                     float* __restrict__ Z,
                     int M, int N, int K)
{
    __shared__ __align__(16) char lds[131072];

    const int tid  = threadIdx.x;
    const int lane = tid & 63;
    const int wid  = tid >> 6;     // 0..7
    const int wr   = wid >> 2;     // 0..1  (128-row half == one virtual batch)
    const int wc   = wid & 3;      // 0..3  (64-col slice)
    const int fr   = lane & 15;
    const int kg   = lane >> 4;

    // XCD-aware bijective swizzle (512 blocks, %8==0)
    const int bid = blockIdx.x;
    const int swz = (bid & 7) * 64 + (bid >> 3);
    const int row0 = (swz >> 2) * 256;
    const int col0 = (swz & 3) * 256;

    // B staging source (gload_lds): row col0+(tid>>2), pre-permuted 16B slot (matches read swz)
    const int sperm = ((tid & 3) ^ ((tid >> 3) & 3)) * 16;
    const char* b0 = (const char*)Bw + (size_t)(col0 + (tid >> 2)) * (size_t)K * 2 + sperm;
    const char* b1 = b0 + (size_t)128 * K * 2;
    const int widB = wid * 1024;

    // A staging source (fp32, reg-staged): thread covers rows (tid>>4)+32j, fp32 cols (tid&15)*4..+3
    const float* aTh = Af + (size_t)(row0 + (tid >> 4)) * (size_t)K + (tid & 15) * 4;

    // A ds_write offsets (within one parity): halfSel*32768 + swz(row*64 + colByte)
    int wA[8];
    {
        const int colByte = (tid & 7) * 8;
        const int halfSel = (tid >> 3) & 1;
        #pragma unroll
        for (int j = 0; j < 8; ++j) {
            int r = (tid >> 4) + 32 * j;
            int ad = r * 64 + colByte;
            ad ^= ((ad >> 7) & 3) << 4;
            wA[j] = halfSel * 32768 + ad;
        }
    }

    // fragment read offsets within a 16KB [256][32] f16 half-buffer, 0-conflict swizzled
    int aoff = (wr * 128 + fr) * 64 + kg * 16;
    aoff ^= ((aoff >> 7) & 3) << 4;
    int boff = (wc * 64 + fr) * 64 + kg * 16;
    boff ^= ((boff >> 7) & 3) << 4;

    f32x4 acc[8][4];
    #pragma unroll
    for (int m = 0; m < 8; ++m)
        #pragma unroll
        for (int n = 0; n < 4; ++n)
            acc[m][n] = (f32x4)0.0f;

    const int nt = K >> 6;   // 32 K-tiles of 64

    // prologue: tile 0 -> parity 0 (A via regs+cvt, B via gload_lds)
    {
        float4 r0[8];
        #pragma unroll
        for (int j = 0; j < 8; ++j)
            r0[j] = *(const float4*)(aTh + (size_t)(32 * j) * K);
        async16(b0,      LDSB(0, 0) + widB);
        async16(b1,      LDSB(0, 0) + 8192 + widB);
        async16(b0 + 64, LDSB(1, 0) + widB);
        async16(b1 + 64, LDSB(1, 0) + 8192 + widB);
        asm volatile("s_waitcnt vmcnt(0)" ::: "memory");
        #pragma unroll
        for (int j = 0; j < 8; ++j) cvtWrite(lds + wA[j], r0[j]);
        asm volatile("s_waitcnt lgkmcnt(0)" ::: "memory");
        __builtin_amdgcn_s_barrier();
    }

    for (int kt = 0; kt < nt - 1; ++kt)
        ktile<true>(kt, lds, aTh, b0, b1, widB, aoff, boff, wA, acc, K);
    ktile<false>(nt - 1, lds, aTh, b0, b1, widB, aoff, boff, wA, acc, K);

    // ---- fused Ghost BatchNorm + priors epilogue (wave-local: wr half = one VBS) ----
    #pragma unroll
    for (int n = 0; n < 4; ++n) {
        float s1 = 0.f, s2 = 0.f;
        #pragma unroll
        for (int m = 0; m < 8; ++m)
            #pragma unroll
            for (int j = 0; j < 4; ++j) {
                float v = acc[m][n][j];
                s1 += v; s2 += v * v;
            }
        s1 += __shfl_xor(s1, 16); s2 += __shfl_xor(s2, 16);
        s1 += __shfl_xor(s1, 32); s2 += __shfl_xor(s2, 32);
        float mean = s1 * (1.f / 128.f);
        float var  = s2 * (1.f / 128.f) - mean * mean;
        float rstd = rsqrtf(var + BN_EPS);
        const int c = col0 + wc * 64 + n * 16 + fr;
        float g = gamma[c] * rstd;
        float b = beta[c] - mean * g;
        #pragma unroll
        for (int m = 0; m < 8; ++m)
            #pragma unroll
            for (int j = 0; j < 4; ++j) {
                int r = row0 + wr * 128 + m * 16 + kg * 4 + j;
                size_t off = (size_t)r * N + c;
                Z[off] = (acc[m][n][j] * g + b) * priors[off];
            }
    }
}

// ---------------- sparsemax: one wave per row of 1024, exact Michelot projection ----------------
__device__ __forceinline__ float waveSum(float v) {
    #pragma unroll
    for (int off = 32; off > 0; off >>= 1) v += __shfl_xor(v, off);
    return v;
}

__global__ __launch_bounds__(256)
void sparsemax_kernel(float* __restrict__ Z) {
    const int lane = threadIdx.x & 63;
    const int wid  = threadIdx.x >> 6;
    const size_t row = (size_t)blockIdx.x * 4 + wid;
    float4* zr4 = (float4*)(Z + row * 1024);

    float p[16];
    #pragma unroll
    for (int j = 0; j < 4; ++j) {
        float4 t = zr4[lane * 4 + j];
        p[4 * j + 0] = t.x; p[4 * j + 1] = t.y; p[4 * j + 2] = t.z; p[4 * j + 3] = t.w;
    }

    float s = 0.f;
    #pragma unroll
    for (int i = 0; i < 16; ++i) s += p[i];
    s = waveSum(s);

    float kc  = 1024.f;
    float tau = (s - 1.f) * (1.f / 1024.f);
    for (int it = 0; it < 64; ++it) {
        float s2 = 0.f, c2 = 0.f;
        #pragma unroll
        for (int i = 0; i < 16; ++i) {
            if (p[i] > tau) { s2 += p[i]; c2 += 1.f; }
        }
        s2 = waveSum(s2); c2 = waveSum(c2);
        if (c2 == kc) break;        // support stable -> tau exact
        kc = c2;
        tau = (s2 - 1.f) / c2;
    }

    #pragma unroll
    for (int j = 0; j < 4; ++j) {
        float4 o;
        o.x = fmaxf(p[4 * j + 0] - tau, 0.f);
        o.y = fmaxf(p[4 * j + 1] - tau, 0.f);
        o.z = fmaxf(p[4 * j + 2] - tau, 0.f);
        o.w = fmaxf(p[4 * j + 3] - tau, 0.f);
        zr4[lane * 4 + j] = o;
    }
}

extern "C" void kernel_launch(void* const* d_in, const int* in_sizes, int n_in,
                              void* d_out, int out_size, void* d_ws, size_t ws_size,
                              hipStream_t stream)
{
    const float* priors = (const float*)d_in[0];
    const float* feat   = (const float*)d_in[1];
    const float* W      = (const float*)d_in[2];
    const float* gamma  = (const float*)d_in[3];
    const float* beta   = (const float*)d_in[4];
    float* out = (float*)d_out;

    const int Nf = in_sizes[3];              // 1024
    const int Kf = in_sizes[2] / Nf;         // 2048
    const int Mr = in_sizes[1] / Kf;         // 32768

    _Float16* Wh = (_Float16*)d_ws;          // N*K*2 = 4 MB (only W is pre-cast now)

    {
        int n8 = Nf * (Kf / 8);
        cast_f32_f16<<<(n8 + 255) / 256, 256, 0, stream>>>(W, Wh, n8);
    }

    int nblk = (Mr / 256) * (Nf / 256);      // 512, divisible by 8
    gemm_gbn_kernel<<<nblk, 512, 0, stream>>>(feat, Wh, priors, gamma, beta, out, Mr, Nf, Kf);

    sparsemax_kernel<<<Mr / 4, 256, 0, stream>>>(out);
}

// Round 11
// 290.456 us; speedup vs baseline: 1.2705x; 1.2705x over previous
//
#include <hip/hip_runtime.h>
#include <hip/hip_bf16.h>
#include <cstdint>

typedef __attribute__((ext_vector_type(4))) float f32x4;
typedef _Float16 f16x8 __attribute__((ext_vector_type(8)));

#define BN_EPS 1e-5f

// ---------------- fp32 -> fp16 cast (only W, 4 MB) ----------------
__global__ __launch_bounds__(256)
void cast_f32_f16(const float* __restrict__ src, _Float16* __restrict__ dst, int n8) {
    int i = blockIdx.x * blockDim.x + threadIdx.x;
    if (i >= n8) return;
    const float4* s4 = (const float4*)src;
    float4 a = s4[2 * (size_t)i];
    float4 b = s4[2 * (size_t)i + 1];
    f16x8 h;
    h[0] = (_Float16)a.x; h[1] = (_Float16)a.y; h[2] = (_Float16)a.z; h[3] = (_Float16)a.w;
    h[4] = (_Float16)b.x; h[5] = (_Float16)b.y; h[6] = (_Float16)b.z; h[7] = (_Float16)b.w;
    *(f16x8*)(dst + 8 * (size_t)i) = h;
}

// async global->LDS, 16B per lane, wave-uniform LDS base
__device__ __forceinline__ void async16(const char* g, char* l) {
    __builtin_amdgcn_global_load_lds(
        (const __attribute__((address_space(1))) unsigned int*)(uintptr_t)g,
        (__attribute__((address_space(3))) unsigned int*)(uintptr_t)l,
        16, 0, 0);
}

// ====== r4 core + A kept fp32 in LDS (fused cast in read path): 256x256, BK=32, 3-buf ======
// A fp32 [256][32] = 32KB/buf via global_load_lds (linear dest, pre-permuted src — NO ds_write).
// B f16  [256][32] = 16KB/buf, r4's proven path. LDS = 3*(32+16) = 144KB.
// A swizzle (128B rows): phys_slot = logical_slot ^ (row&7). Read b128: 64 lanes -> 8 lanes
// per 16B slot -> 8-cycle wave minimum, conflict-free (enumerated). Source involution:
// sperm = ((t&7)^((t>>3)&7))*16, dest row = t>>3 per 8KB issue.
// Per tile: stage(kt+2) [A x4 + B x2 issues]; 16 A ds_read_b128 + cvt + 4 B ds_read_b128;
// 32 MFMA (setprio); vmcnt(6) [retires kt+1]; barrier. Prologue stage(0,1), vmcnt(6).
// Tail: vmcnt(0) at nt-2. Buffer (kt+2)%3 == (kt-1)%3 safe: kt-1's reads consumed (lgkm)
// before its closing barrier, which precedes this stage.

#define ABUF(t) (lds + ((t) % 3) * 32768)
#define BBUF(t) (lds + 98304 + ((t) % 3) * 16384)

__device__ __forceinline__ void stageTile(int t, char* lds,
                                          const char* aT, const char* bT,
                                          int wid, size_t K4, size_t K2) {
    char* dA = ABUF(t) + wid * 1024;
    const char* sA = aT + (size_t)t * 128;
    #pragma unroll
    for (int i = 0; i < 4; ++i)
        async16(sA + (size_t)i * 64 * K4, dA + i * 8192);
    char* dB = BBUF(t) + wid * 1024;
    const char* sB = bT + (size_t)t * 64;
    async16(sB, dB);
    async16(sB + (size_t)128 * K2, dB + 8192);
}

template<int WAITSEL, bool STAGE, bool BAR>
__device__ __forceinline__ void ktile(
    int kt, char* lds, const char* aT, const char* bT,
    int wid, int aoffA, int boff, size_t K4, size_t K2, f32x4 (&acc)[8][4])
{
    if (STAGE) stageTile(kt + 2, lds, aT, bT, wid, K4, K2);
    const char* ab = ABUF(kt);
    const char* bb = BBUF(kt);
    f16x8 a[8], b[4];
    #pragma unroll
    for (int n = 0; n < 4; ++n) b[n] = *(const f16x8*)(bb + boff + n * 1024);
    #pragma unroll
    for (int m = 0; m < 8; ++m) {
        f32x4 lo = *(const f32x4*)(ab + (aoffA + m * 2048));
        f32x4 hi = *(const f32x4*)(ab + ((aoffA + m * 2048) ^ 16));
        f16x8 h;
        h[0] = (_Float16)lo[0]; h[1] = (_Float16)lo[1];
        h[2] = (_Float16)lo[2]; h[3] = (_Float16)lo[3];
        h[4] = (_Float16)hi[0]; h[5] = (_Float16)hi[1];
        h[6] = (_Float16)hi[2]; h[7] = (_Float16)hi[3];
        a[m] = h;
    }
    __builtin_amdgcn_s_setprio(1);
    #pragma unroll
    for (int m = 0; m < 8; ++m)
        #pragma unroll
        for (int n = 0; n < 4; ++n)
            acc[m][n] = __builtin_amdgcn_mfma_f32_16x16x32_f16(a[m], b[n], acc[m][n], 0, 0, 0);
    __builtin_amdgcn_s_setprio(0);
    if (WAITSEL == 2)      { asm volatile("s_waitcnt vmcnt(6)" ::: "memory"); }
    else if (WAITSEL == 1) { asm volatile("s_waitcnt vmcnt(0)" ::: "memory"); }
    if (BAR) __builtin_amdgcn_s_barrier();
}

__global__ __launch_bounds__(512, 2)
void gemm_gbn_kernel(const float* __restrict__ Af,
                     const _Float16* __restrict__ Bw,
                     const float* __restrict__ priors,
                     const float* __restrict__ gamma,
                     const float* __restrict__ beta,
                     float* __restrict__ Z,
                     int M, int N, int K)
{
    __shared__ __align__(16) char lds[147456];   // 144 KB

    const int tid  = threadIdx.x;
    const int lane = tid & 63;
    const int wid  = tid >> 6;     // 0..7
    const int wr   = wid >> 2;     // 0..1  (128-row half == one virtual batch)
    const int wc   = wid & 3;      // 0..3  (64-col slice)
    const int fr   = lane & 15;
    const int kg   = lane >> 4;
    const size_t K4 = (size_t)K * 4;
    const size_t K2 = (size_t)K * 2;

    // XCD-aware bijective swizzle (512 blocks, %8==0)
    const int bid = blockIdx.x;
    const int swz = (bid & 7) * 64 + (bid >> 3);
    const int row0 = (swz >> 2) * 256;
    const int col0 = (swz & 3) * 256;

    // A staging source: fp32, issue i covers rows i*64 + (tid>>3); 8 slots of 16B per 128B
    // row-tile; pre-permuted slot = (tid&7)^((tid>>3)&7) (involution matching read swizzle)
    const int aperm = ((tid & 7) ^ ((tid >> 3) & 7)) * 16;
    const char* aT = (const char*)Af + (size_t)(row0 + (tid >> 3)) * K4 + aperm;

    // B staging source: f16, issue j covers rows j*128 + (tid>>2); 4 slots of 16B per 64B
    const int bperm = ((tid & 3) ^ ((tid >> 3) & 3)) * 16;
    const char* bT = (const char*)Bw + (size_t)(col0 + (tid >> 2)) * K2 + bperm;

    // A fragment read base ([256][32] fp32, 128B rows): row = wr*128 + m*16 + fr,
    // logical slots kg*2, kg*2+1; physical slot = logical ^ (fr&7); second read = first ^ 16.
    const int aoffA = (wr * 128 + fr) * 128 + (((kg * 2) ^ (fr & 7)) * 16);

    // B fragment read base ([256][32] f16, 64B rows), r4's proven 0-conflict swizzle
    int boff = (wc * 64 + fr) * 64 + kg * 16;
    boff ^= ((boff >> 7) & 3) << 4;

    f32x4 acc[8][4];
    #pragma unroll
    for (int m = 0; m < 8; ++m)
        #pragma unroll
        for (int n = 0; n < 4; ++n)
            acc[m][n] = (f32x4)0.0f;

    // prologue: stage tiles 0,1; vmcnt(6) -> tile 0 resident, tile 1 in flight
    stageTile(0, lds, aT, bT, wid, K4, K2);
    stageTile(1, lds, aT, bT, wid, K4, K2);
    asm volatile("s_waitcnt vmcnt(6)" ::: "memory");
    __builtin_amdgcn_s_barrier();

    const int nt = K >> 5;                 // 64 K-tiles of 32
    for (int kt = 0; kt < nt - 2; ++kt)
        ktile<2, true,  true >(kt, lds, aT, bT, wid, aoffA, boff, K4, K2, acc);
    ktile<1, false, true >(nt - 2, lds, aT, bT, wid, aoffA, boff, K4, K2, acc);
    ktile<0, false, false>(nt - 1, lds, aT, bT, wid, aoffA, boff, K4, K2, acc);

    // ---- fused Ghost BatchNorm + priors epilogue (wave-local: wr half = one VBS) ----
    #pragma unroll
    for (int n = 0; n < 4; ++n) {
        float s1 = 0.f, s2 = 0.f;
        #pragma unroll
        for (int m = 0; m < 8; ++m)
            #pragma unroll
            for (int j = 0; j < 4; ++j) {
                float v = acc[m][n][j];
                s1 += v; s2 += v * v;
            }
        s1 += __shfl_xor(s1, 16); s2 += __shfl_xor(s2, 16);
        s1 += __shfl_xor(s1, 32); s2 += __shfl_xor(s2, 32);
        float mean = s1 * (1.f / 128.f);
        float var  = s2 * (1.f / 128.f) - mean * mean;
        float rstd = rsqrtf(var + BN_EPS);
        const int c = col0 + wc * 64 + n * 16 + fr;
        float g = gamma[c] * rstd;
        float b = beta[c] - mean * g;
        #pragma unroll
        for (int m = 0; m < 8; ++m)
            #pragma unroll
            for (int j = 0; j < 4; ++j) {
                int r = row0 + wr * 128 + m * 16 + kg * 4 + j;
                size_t off = (size_t)r * N + c;
                Z[off] = (acc[m][n][j] * g + b) * priors[off];
            }
    }
}

// ---------------- sparsemax: one wave per row of 1024, exact Michelot projection ----------------
__device__ __forceinline__ float waveSum(float v) {
    #pragma unroll
    for (int off = 32; off > 0; off >>= 1) v += __shfl_xor(v, off);
    return v;
}

__global__ __launch_bounds__(256)
void sparsemax_kernel(float* __restrict__ Z) {
    const int lane = threadIdx.x & 63;
    const int wid  = threadIdx.x >> 6;
    const size_t row = (size_t)blockIdx.x * 4 + wid;
    float4* zr4 = (float4*)(Z + row * 1024);

    float p[16];
    #pragma unroll
    for (int j = 0; j < 4; ++j) {
        float4 t = zr4[lane * 4 + j];
        p[4 * j + 0] = t.x; p[4 * j + 1] = t.y; p[4 * j + 2] = t.z; p[4 * j + 3] = t.w;
    }

    float s = 0.f;
    #pragma unroll
    for (int i = 0; i < 16; ++i) s += p[i];
    s = waveSum(s);

    float kc  = 1024.f;
    float tau = (s - 1.f) * (1.f / 1024.f);
    for (int it = 0; it < 64; ++it) {
        float s2 = 0.f, c2 = 0.f;
        #pragma unroll
        for (int i = 0; i < 16; ++i) {
            if (p[i] > tau) { s2 += p[i]; c2 += 1.f; }
        }
        s2 = waveSum(s2); c2 = waveSum(c2);
        if (c2 == kc) break;        // support stable -> tau exact
        kc = c2;
        tau = (s2 - 1.f) / c2;
    }

    #pragma unroll
    for (int j = 0; j < 4; ++j) {
        float4 o;
        o.x = fmaxf(p[4 * j + 0] - tau, 0.f);
        o.y = fmaxf(p[4 * j + 1] - tau, 0.f);
        o.z = fmaxf(p[4 * j + 2] - tau, 0.f);
        o.w = fmaxf(p[4 * j + 3] - tau, 0.f);
        zr4[lane * 4 + j] = o;
    }
}

extern "C" void kernel_launch(void* const* d_in, const int* in_sizes, int n_in,
                              void* d_out, int out_size, void* d_ws, size_t ws_size,
                              hipStream_t stream)
{
    const float* priors = (const float*)d_in[0];
    const float* feat   = (const float*)d_in[1];
    const float* W      = (const float*)d_in[2];
    const float* gamma  = (const float*)d_in[3];
    const float* beta   = (const float*)d_in[4];
    float* out = (float*)d_out;

    const int Nf = in_sizes[3];              // 1024
    const int Kf = in_sizes[2] / Nf;         // 2048
    const int Mr = in_sizes[1] / Kf;         // 32768

    _Float16* Wh = (_Float16*)d_ws;          // N*K*2 = 4 MB (only W is pre-cast)

    {
        int n8 = Nf * (Kf / 8);
        cast_f32_f16<<<(n8 + 255) / 256, 256, 0, stream>>>(W, Wh, n8);
    }

    int nblk = (Mr / 256) * (Nf / 256);      // 512, divisible by 8
    gemm_gbn_kernel<<<nblk, 512, 0, stream>>>(feat, Wh, priors, gamma, beta, out, Mr, Nf, Kf);

    sparsemax_kernel<<<Mr / 4, 256, 0, stream>>>(out);
}